// Round 3
// baseline (333.445 us; speedup 1.0000x reference)
//
#include <hip/hip_runtime.h>
#include <hip/hip_cooperative_groups.h>

namespace cg = cooperative_groups;

#define H 200
#define D 768
#define BATCH 4
#define S 512
#define M (BATCH*S)     // 2048
#define KP 224          // H padded to mult of 32 (MFMA K-step)
#define NP 208          // H padded to mult of 16 (hv N-dim)
#define NCAT 400        // head|tail concatenated output cols
#define OG 8            // o-split groups in reduceU
#define GBLK 512        // cooperative grid blocks
#define NTHREADS 256

typedef __attribute__((ext_vector_type(8))) short bf16x8;   // 8 bf16 (4 VGPRs)
typedef __attribute__((ext_vector_type(4))) float f32x4;
typedef unsigned short us;

__device__ inline us f2bf(float f) {            // round-to-nearest-even fp32->bf16
    union { float f; unsigned u; } v; v.f = f;
    return (us)((v.u + 0x7FFF + ((v.u >> 16) & 1)) >> 16);
}

// ---------------------------------------------------------------------------
// Single cooperative kernel; phases separated by grid.sync().
//  P1: cvt x->bf16, cvt+transpose W->bf16, reduceU o-partials (HBM floor 32MB)
//  P2: finish V (transpose+bf16), zero pad cols, proj MFMA (relu(xW+b))
//  P3: hv = head @ V^T  MFMA
//  P4: scores = hv . tail^T MFMA + bias + scale
// MFMA fragment conventions identical to the round-2 kernels (verified).
// ---------------------------------------------------------------------------
__global__ __launch_bounds__(NTHREADS) void mega(
        const float* __restrict__ x,  const float* __restrict__ Wh,
        const float* __restrict__ bh, const float* __restrict__ Wt,
        const float* __restrict__ bt, const float* __restrict__ U,
        const float* __restrict__ Wd, const float* __restrict__ bd,
        float* __restrict__ out, unsigned char* __restrict__ ws) {
    cg::grid_group grid = cg::this_grid();

    // workspace layout
    us* xb    = (us*)ws;                         // [M*D]
    us* Wcb   = xb    + (size_t)M * D;           // [NCAT*D]  rows n, cols k
    us* VTb   = Wcb   + (size_t)NCAT * D;        // [NP*KP]   V^T, zero-padded
    us* hvb   = VTb   + (size_t)NP * KP;         // [M*KP]
    us* headb = hvb   + (size_t)M * KP;          // [M*KP]
    us* tailb = headb + (size_t)M * KP;          // [M*KP]
    float* P  = (float*)(tailb + (size_t)M * KP);// [OG*H*H] fp32 partials

    const int gtid = blockIdx.x * NTHREADS + threadIdx.x;
    const int GTH  = GBLK * NTHREADS;            // 131072
    const int wid  = gtid >> 6;                  // global wave id, 0..2047
    const int lane = threadIdx.x & 63;
    const int quad = lane >> 4, col = lane & 15;

    // ======================= Phase 1 =======================
    {   // x -> bf16 (vectorized, M*D/4 = 393216 exact multiples)
        const float4* x4 = (const float4*)x;
        ushort4* xb4 = (ushort4*)xb;
        for (int t = gtid; t < M * D / 4; t += GTH) {
            float4 v = x4[t];
            ushort4 o; o.x = f2bf(v.x); o.y = f2bf(v.y); o.z = f2bf(v.z); o.w = f2bf(v.w);
            xb4[t] = o;
        }
        // W transpose+concat -> bf16 : Wcb[n*D+k]
        for (int id = gtid; id < NCAT * D; id += GTH) {
            int n = id / D, k = id % D;
            float v = (n < H) ? Wh[k * H + n] : Wt[k * H + (n - H)];
            Wcb[id] = f2bf(v);
        }
        // reduceU partials: P[g][i*H+j] = sum_{o in group g} Wd[o]*U[o,i,j]
        const float4* U4 = (const float4*)U;
        float4* P4 = (float4*)P;
        for (int task = gtid; task < OG * (H * H / 4); task += GTH) {
            int g = task / (H * H / 4), t = task % (H * H / 4);
            float4 acc = make_float4(0.f, 0.f, 0.f, 0.f);
            int o0 = g * (H / OG);
            #pragma unroll 5
            for (int o = o0; o < o0 + H / OG; ++o) {
                float w = Wd[o];
                float4 u = U4[o * (H * H / 4) + t];
                acc.x += w * u.x; acc.y += w * u.y; acc.z += w * u.z; acc.w += w * u.w;
            }
            P4[g * (H * H / 4) + t] = acc;
        }
    }
    grid.sync();

    // ======================= Phase 2 =======================
    {   // zero pad cols [H..KP) of headb/tailb, [NP..KP) of hvb
        for (int id = gtid; id < M * (KP - H); id += GTH) {
            int r = id / (KP - H), c = H + id % (KP - H);
            headb[r * KP + c] = 0; tailb[r * KP + c] = 0;
        }
        for (int id = gtid; id < M * (KP - NP); id += GTH) {
            int r = id / (KP - NP), c = NP + id % (KP - NP);
            hvb[r * KP + c] = 0;
        }
        // VTb[n*KP+k] = V[k][n] = sum_g P[g][k*H+n]  (zero-padded)
        for (int id = gtid; id < NP * KP; id += GTH) {
            int n = id / KP, k = id % KP;
            float s = 0.f;
            if (n < H && k < H) {
                #pragma unroll
                for (int g = 0; g < OG; ++g) s += P[g * H * H + k * H + n];
            }
            VTb[id] = f2bf(s);
        }
        // proj: one wave per 32x16 tile of [M, NCAT]
        if (wid < (M / 32) * (NCAT / 16)) {
            int m0 = (wid % (M / 32)) * 32, n0 = (wid / (M / 32)) * 16;
            const bf16x8* A0 = (const bf16x8*)(xb + (m0 + col) * D + quad * 8);
            const bf16x8* A1 = (const bf16x8*)(xb + (m0 + 16 + col) * D + quad * 8);
            const bf16x8* Bp = (const bf16x8*)(Wcb + (n0 + col) * D + quad * 8);
            f32x4 acc0 = {0.f,0.f,0.f,0.f}, acc1 = {0.f,0.f,0.f,0.f};
            #pragma unroll 4
            for (int kk = 0; kk < D / 32; ++kk) {
                bf16x8 a0 = A0[kk * 4];
                bf16x8 a1 = A1[kk * 4];
                bf16x8 b  = Bp[kk * 4];
                acc0 = __builtin_amdgcn_mfma_f32_16x16x32_bf16(a0, b, acc0, 0, 0, 0);
                acc1 = __builtin_amdgcn_mfma_f32_16x16x32_bf16(a1, b, acc1, 0, 0, 0);
            }
            int n = n0 + col;
            float bias; us* dst; int nn;
            if (n < H) { bias = bh[n];     dst = headb; nn = n; }
            else       { bias = bt[n - H]; dst = tailb; nn = n - H; }
            #pragma unroll
            for (int r = 0; r < 4; ++r) {
                int ma = m0 + quad * 4 + r;
                dst[ma * KP + nn]        = f2bf(fmaxf(acc0[r] + bias, 0.f));
                dst[(ma + 16) * KP + nn] = f2bf(fmaxf(acc1[r] + bias, 0.f));
            }
        }
    }
    grid.sync();

    // ======================= Phase 3 =======================
    // hv[M,NP] = headb[M,KP] @ VTb[NP,KP]^T ; one wave per 32x16 tile
    if (wid < (M / 32) * (NP / 16)) {
        int m0 = (wid % (M / 32)) * 32, n0 = (wid / (M / 32)) * 16;
        const bf16x8* A0 = (const bf16x8*)(headb + (m0 + col) * KP + quad * 8);
        const bf16x8* A1 = (const bf16x8*)(headb + (m0 + 16 + col) * KP + quad * 8);
        const bf16x8* Bp = (const bf16x8*)(VTb + (n0 + col) * KP + quad * 8);
        f32x4 acc0 = {0.f,0.f,0.f,0.f}, acc1 = {0.f,0.f,0.f,0.f};
        #pragma unroll
        for (int kk = 0; kk < KP / 32; ++kk) {
            bf16x8 a0 = A0[kk * 4];
            bf16x8 a1 = A1[kk * 4];
            bf16x8 b  = Bp[kk * 4];
            acc0 = __builtin_amdgcn_mfma_f32_16x16x32_bf16(a0, b, acc0, 0, 0, 0);
            acc1 = __builtin_amdgcn_mfma_f32_16x16x32_bf16(a1, b, acc1, 0, 0, 0);
        }
        int n = n0 + col;
        #pragma unroll
        for (int r = 0; r < 4; ++r) {
            int ma = m0 + quad * 4 + r;
            hvb[ma * KP + n]        = f2bf(acc0[r]);
            hvb[(ma + 16) * KP + n] = f2bf(acc1[r]);
        }
    }
    grid.sync();

    // ======================= Phase 4 =======================
    // scores[b,x,y]; one wave per 32x16 tile; 4*16*32 = 2048 tiles = all waves
    {
        int b  = wid >> 9;
        int r9 = wid & 511;
        int m0 = (r9 & 15) * 32, n0 = (r9 >> 4) * 16;
        const us* A  = hvb   + (size_t)b * S * KP;
        const us* Bm = tailb + (size_t)b * S * KP;
        const bf16x8* A0 = (const bf16x8*)(A  + (m0 + col) * KP + quad * 8);
        const bf16x8* A1 = (const bf16x8*)(A  + (m0 + 16 + col) * KP + quad * 8);
        const bf16x8* Bp = (const bf16x8*)(Bm + (n0 + col) * KP + quad * 8);
        f32x4 acc0 = {0.f,0.f,0.f,0.f}, acc1 = {0.f,0.f,0.f,0.f};
        #pragma unroll
        for (int kk = 0; kk < KP / 32; ++kk) {
            bf16x8 a0 = A0[kk * 4];
            bf16x8 a1 = A1[kk * 4];
            bf16x8 b8 = Bp[kk * 4];
            acc0 = __builtin_amdgcn_mfma_f32_16x16x32_bf16(a0, b8, acc0, 0, 0, 0);
            acc1 = __builtin_amdgcn_mfma_f32_16x16x32_bf16(a1, b8, acc1, 0, 0, 0);
        }
        float bias = bd[0];
        const float scale = 0.07071067811865475f;   // 1/sqrt(200)
        float* outb = out + (size_t)b * S * S;
        #pragma unroll
        for (int r = 0; r < 4; ++r) {
            int ma = m0 + quad * 4 + r;
            outb[ma * S + n0 + col]        = (acc0[r] + bias) * scale;
            outb[(ma + 16) * S + n0 + col] = (acc1[r] + bias) * scale;
        }
    }
}

extern "C" void kernel_launch(void* const* d_in, const int* in_sizes, int n_in,
                              void* d_out, int out_size, void* d_ws, size_t ws_size,
                              hipStream_t stream) {
    const void* x  = d_in[0];
    const void* Wh = d_in[1];
    const void* bh = d_in[2];
    const void* Wt = d_in[3];
    const void* bt = d_in[4];
    const void* U  = d_in[5];
    const void* Wd = d_in[6];
    const void* bd = d_in[7];
    void* outp = d_out;
    void* wsp  = d_ws;
    void* args[] = { &x, &Wh, &bh, &Wt, &bt, &U, &Wd, &bd, &outp, &wsp };
    hipLaunchCooperativeKernel((void*)mega, dim3(GBLK), dim3(NTHREADS),
                               args, 0, stream);
}

// Round 4
// 119.727 us; speedup vs baseline: 2.7850x; 2.7850x over previous
//
#include <hip/hip_runtime.h>

#define H 200
#define D 768
#define BATCH 4
#define S 512
#define M (BATCH*S)     // 2048
#define KP 224          // H padded to mult of 32 (MFMA K-step)
#define NP 208          // H padded to mult of 16 (hv N-dim)
#define NCAT 400        // head|tail concatenated output cols
#define VT_BLOCKS 79    // ceil(10000 float4-cols / 128)
#define PREP_BLOCKS 1000

typedef __attribute__((ext_vector_type(8))) short bf16x8;   // 8 bf16 (4 VGPRs)
typedef __attribute__((ext_vector_type(4))) float f32x4;
typedef unsigned short us;

__device__ inline us f2bf(float f) {            // round-to-nearest-even fp32->bf16
    union { float f; unsigned u; } v; v.f = f;
    return (us)((v.u + 0x7FFF + ((v.u >> 16) & 1)) >> 16);
}

// ---------------------------------------------------------------------------
// prep: blocks [0,VT_BLOCKS) -> V reduction (block-local o-split, LDS combine),
// remaining blocks grid-stride { x->bf16, W->bf16 transposed+concat, pads }.
// Replaces 4 kernels + 2 memsets from round 2 with ONE dispatch.
// ---------------------------------------------------------------------------
__global__ __launch_bounds__(256) void prep(
        const float* __restrict__ x,  const float* __restrict__ Wh,
        const float* __restrict__ Wt, const float* __restrict__ U,
        const float* __restrict__ Wd,
        us* __restrict__ xb, us* __restrict__ Wcb, us* __restrict__ VTb,
        us* __restrict__ headb, us* __restrict__ tailb, us* __restrict__ hvb) {
    int bid = blockIdx.x;
    if (bid < VT_BLOCKS) {
        // thread (c,half): float4-column t0+c of V, o-range [half*100,(half+1)*100)
        __shared__ float4 red[128];
        int c = threadIdx.x & 127, half = threadIdx.x >> 7;
        int t = bid * 128 + c;                   // float4 index into V[H*H]
        const float4* U4 = (const float4*)U;
        float4 acc = make_float4(0.f, 0.f, 0.f, 0.f);
        if (t < H * H / 4) {
            int o0 = half * (H / 2);
            #pragma unroll 10
            for (int o = o0; o < o0 + H / 2; ++o) {
                float w = Wd[o];
                float4 u = U4[o * (H * H / 4) + t];   // coalesced 1KB/wave
                acc.x += w * u.x; acc.y += w * u.y;
                acc.z += w * u.z; acc.w += w * u.w;
            }
        }
        if (half == 1) red[c] = acc;
        __syncthreads();
        if (half == 0 && t < H * H / 4) {
            float4 r = red[c];
            acc.x += r.x; acc.y += r.y; acc.z += r.z; acc.w += r.w;
            int i = t / (H / 4), j0 = (t % (H / 4)) * 4;  // V row i, cols j0..j0+3
            VTb[(j0 + 0) * KP + i] = f2bf(acc.x);         // VTb[n][k] = V[k][n]
            VTb[(j0 + 1) * KP + i] = f2bf(acc.y);
            VTb[(j0 + 2) * KP + i] = f2bf(acc.z);
            VTb[(j0 + 3) * KP + i] = f2bf(acc.w);
        }
        return;
    }
    const int GTH = (PREP_BLOCKS - VT_BLOCKS) * 256;
    int gtid = (bid - VT_BLOCKS) * 256 + threadIdx.x;
    // x -> bf16 (float4-vectorized; M*D/4 = 393216)
    {
        const float4* x4 = (const float4*)x;
        ushort4* xb4 = (ushort4*)xb;
        for (int t = gtid; t < M * D / 4; t += GTH) {
            float4 v = x4[t];
            ushort4 o; o.x = f2bf(v.x); o.y = f2bf(v.y); o.z = f2bf(v.z); o.w = f2bf(v.w);
            xb4[t] = o;
        }
    }
    // W transpose+concat -> bf16: Wcb[n*D+k] = W{h|t}[k][n]
    for (int id = gtid; id < NCAT * D; id += GTH) {
        int n = id / D, k = id % D;
        float v = (n < H) ? Wh[k * H + n] : Wt[k * H + (n - H)];
        Wcb[id] = f2bf(v);
    }
    // pad zeroing (ws is poisoned 0xAA every call): headb/tailb K-pad cols,
    // hvb K-pad cols, VTb pad region
    for (int id = gtid; id < M * (KP - H); id += GTH) {
        int r = id / (KP - H), c = H + id % (KP - H);
        headb[r * KP + c] = 0; tailb[r * KP + c] = 0;
    }
    for (int id = gtid; id < M * (KP - NP); id += GTH) {
        int r = id / (KP - NP), c = NP + id % (KP - NP);
        hvb[r * KP + c] = 0;
    }
    for (int id = gtid; id < H * (KP - H); id += GTH) {      // n<H, k in [H,KP)
        int n = id / (KP - H), k = H + id % (KP - H);
        VTb[n * KP + k] = 0;
    }
    for (int id = gtid; id < (NP - H) * KP; id += GTH) {     // n in [H,NP), all k
        int n = H + id / KP, k = id % KP;
        VTb[n * KP + k] = 0;
    }
}

// ---------------------------------------------------------------------------
// proj: C[2048,400] = xb[2048,768] @ Wcb^T; relu(+bias); split into headb|tailb
// One wave per 32x16 tile (verified round 2).
// ---------------------------------------------------------------------------
__global__ __launch_bounds__(64) void proj_mfma(
        const us* __restrict__ xb, const us* __restrict__ Wcb,
        const float* __restrict__ bh, const float* __restrict__ bt,
        us* __restrict__ headb, us* __restrict__ tailb) {
    int lane = threadIdx.x, quad = lane >> 4, col = lane & 15;
    int m0 = blockIdx.x * 32, n0 = blockIdx.y * 16;
    const bf16x8* A0 = (const bf16x8*)(xb + (m0 + col) * D + quad * 8);
    const bf16x8* A1 = (const bf16x8*)(xb + (m0 + 16 + col) * D + quad * 8);
    const bf16x8* Bp = (const bf16x8*)(Wcb + (n0 + col) * D + quad * 8);
    f32x4 acc0 = {0.f,0.f,0.f,0.f}, acc1 = {0.f,0.f,0.f,0.f};
    #pragma unroll 4
    for (int kk = 0; kk < D / 32; ++kk) {
        bf16x8 a0 = A0[kk * 4];
        bf16x8 a1 = A1[kk * 4];
        bf16x8 b  = Bp[kk * 4];
        acc0 = __builtin_amdgcn_mfma_f32_16x16x32_bf16(a0, b, acc0, 0, 0, 0);
        acc1 = __builtin_amdgcn_mfma_f32_16x16x32_bf16(a1, b, acc1, 0, 0, 0);
    }
    int n = n0 + col;
    float bias; us* dst; int nn;
    if (n < H) { bias = bh[n];     dst = headb; nn = n; }
    else       { bias = bt[n - H]; dst = tailb; nn = n - H; }
    #pragma unroll
    for (int r = 0; r < 4; ++r) {
        int ma = m0 + quad * 4 + r;
        dst[ma * KP + nn]        = f2bf(fmaxf(acc0[r] + bias, 0.f));
        dst[(ma + 16) * KP + nn] = f2bf(fmaxf(acc1[r] + bias, 0.f));
    }
}

// ---------------------------------------------------------------------------
// hv[2048,208] = headb[2048,224] @ VTb[208,224]^T
// ---------------------------------------------------------------------------
__global__ __launch_bounds__(64) void hv_mfma(
        const us* __restrict__ headb, const us* __restrict__ VTb,
        us* __restrict__ hvb) {
    int lane = threadIdx.x, quad = lane >> 4, col = lane & 15;
    int m0 = blockIdx.x * 32, n0 = blockIdx.y * 16;
    const bf16x8* A0 = (const bf16x8*)(headb + (m0 + col) * KP + quad * 8);
    const bf16x8* A1 = (const bf16x8*)(headb + (m0 + 16 + col) * KP + quad * 8);
    const bf16x8* Bp = (const bf16x8*)(VTb + (n0 + col) * KP + quad * 8);
    f32x4 acc0 = {0.f,0.f,0.f,0.f}, acc1 = {0.f,0.f,0.f,0.f};
    #pragma unroll
    for (int kk = 0; kk < KP / 32; ++kk) {
        bf16x8 a0 = A0[kk * 4];
        bf16x8 a1 = A1[kk * 4];
        bf16x8 b  = Bp[kk * 4];
        acc0 = __builtin_amdgcn_mfma_f32_16x16x32_bf16(a0, b, acc0, 0, 0, 0);
        acc1 = __builtin_amdgcn_mfma_f32_16x16x32_bf16(a1, b, acc1, 0, 0, 0);
    }
    int n = n0 + col;
    #pragma unroll
    for (int r = 0; r < 4; ++r) {
        int ma = m0 + quad * 4 + r;
        hvb[ma * KP + n]        = f2bf(acc0[r]);
        hvb[(ma + 16) * KP + n] = f2bf(acc1[r]);
    }
}

// ---------------------------------------------------------------------------
// scores[b,x,y] = (hv[b,x,:].tail[b,y,:] + b_down)/sqrt(200); 32x32 per wave
// ---------------------------------------------------------------------------
__global__ __launch_bounds__(64) void scores_mfma(
        const us* __restrict__ hvb, const us* __restrict__ tailb,
        const float* __restrict__ bd, float* __restrict__ out) {
    int lane = threadIdx.x, quad = lane >> 4, col = lane & 15;
    int b = blockIdx.z;
    int m0 = blockIdx.x * 32, n0 = blockIdx.y * 32;
    const us* A  = hvb   + (size_t)b * S * KP;
    const us* Bm = tailb + (size_t)b * S * KP;
    const bf16x8* A0 = (const bf16x8*)(A  + (m0 + col) * KP + quad * 8);
    const bf16x8* A1 = (const bf16x8*)(A  + (m0 + 16 + col) * KP + quad * 8);
    const bf16x8* B0 = (const bf16x8*)(Bm + (n0 + col) * KP + quad * 8);
    const bf16x8* B1 = (const bf16x8*)(Bm + (n0 + 16 + col) * KP + quad * 8);
    f32x4 a00 = {0.f,0.f,0.f,0.f}, a01 = {0.f,0.f,0.f,0.f};
    f32x4 a10 = {0.f,0.f,0.f,0.f}, a11 = {0.f,0.f,0.f,0.f};
    #pragma unroll
    for (int kk = 0; kk < KP / 32; ++kk) {
        bf16x8 a0 = A0[kk * 4];
        bf16x8 a1 = A1[kk * 4];
        bf16x8 b0 = B0[kk * 4];
        bf16x8 b1 = B1[kk * 4];
        a00 = __builtin_amdgcn_mfma_f32_16x16x32_bf16(a0, b0, a00, 0, 0, 0);
        a01 = __builtin_amdgcn_mfma_f32_16x16x32_bf16(a0, b1, a01, 0, 0, 0);
        a10 = __builtin_amdgcn_mfma_f32_16x16x32_bf16(a1, b0, a10, 0, 0, 0);
        a11 = __builtin_amdgcn_mfma_f32_16x16x32_bf16(a1, b1, a11, 0, 0, 0);
    }
    float bias = bd[0];
    const float scale = 0.07071067811865475f;   // 1/sqrt(200)
    float* outb = out + (size_t)b * S * S;
    #pragma unroll
    for (int r = 0; r < 4; ++r) {
        int ma = m0 + quad * 4 + r, mb = ma + 16;
        outb[ma * S + n0 + col]      = (a00[r] + bias) * scale;
        outb[ma * S + n0 + 16 + col] = (a01[r] + bias) * scale;
        outb[mb * S + n0 + col]      = (a10[r] + bias) * scale;
        outb[mb * S + n0 + 16 + col] = (a11[r] + bias) * scale;
    }
}

extern "C" void kernel_launch(void* const* d_in, const int* in_sizes, int n_in,
                              void* d_out, int out_size, void* d_ws, size_t ws_size,
                              hipStream_t stream) {
    const float* x  = (const float*)d_in[0];
    const float* Wh = (const float*)d_in[1];
    const float* bh = (const float*)d_in[2];
    const float* Wt = (const float*)d_in[3];
    const float* bt = (const float*)d_in[4];
    const float* U  = (const float*)d_in[5];
    const float* Wd = (const float*)d_in[6];
    const float* bd = (const float*)d_in[7];
    float* out = (float*)d_out;

    // ws layout (bf16): xb | Wcb | VTb | hvb | headb | tailb  (~6.6 MB)
    us* xb    = (us*)d_ws;
    us* Wcb   = xb    + (size_t)M * D;
    us* VTb   = Wcb   + (size_t)NCAT * D;
    us* hvb   = VTb   + (size_t)NP * KP;
    us* headb = hvb   + (size_t)M * KP;
    us* tailb = headb + (size_t)M * KP;

    prep<<<PREP_BLOCKS, 256, 0, stream>>>(x, Wh, Wt, U, Wd,
                                          xb, Wcb, VTb, headb, tailb, hvb);
    proj_mfma<<<dim3(M / 32, NCAT / 16), 64, 0, stream>>>(xb, Wcb, bh, bt, headb, tailb);
    hv_mfma<<<dim3(M / 32, NP / 16), 64, 0, stream>>>(headb, VTb, hvb);
    scores_mfma<<<dim3(S / 32, S / 32, BATCH), 64, 0, stream>>>(hvb, tailb, bd, out);
}

// Round 5
// 117.016 us; speedup vs baseline: 2.8496x; 1.0232x over previous
//
#include <hip/hip_runtime.h>

#define H 200
#define D 768
#define BATCH 4
#define S 512
#define M (BATCH*S)     // 2048
#define KP 224          // H padded to mult of 32 (MFMA K-step)
#define NP 208          // H padded to mult of 16 (hv N-dim)
#define NCAT 400        // head|tail concatenated output cols
#define NC4 (H*H/4)     // 10000 float4-columns of V
#define VT_BLOCKS 313   // ceil(10000 cols / 32) ; block = 32 cols x 8 o-octs
#define PREP_BLOCKS 1000

typedef __attribute__((ext_vector_type(8))) short bf16x8;   // 8 bf16 (4 VGPRs)
typedef __attribute__((ext_vector_type(4))) float f32x4;
typedef unsigned short us;

__device__ inline us f2bf(float f) {            // round-to-nearest-even fp32->bf16
    union { float f; unsigned u; } v; v.f = f;
    return (us)((v.u + 0x7FFF + ((v.u >> 16) & 1)) >> 16);
}

// ---------------------------------------------------------------------------
// prep: blocks [0,VT_BLOCKS): V = sum_o Wd[o]*U[o] over 32 cols x 8 o-octs
// per block (25-deep full-unroll chains, LDS combine, transposed bf16 store).
// Remaining 687 blocks grid-stride { x->bf16, W->bf16 transposed+concat, pads }.
// ---------------------------------------------------------------------------
__global__ __launch_bounds__(256) void prep(
        const float* __restrict__ x,  const float* __restrict__ Wh,
        const float* __restrict__ Wt, const float* __restrict__ U,
        const float* __restrict__ Wd,
        us* __restrict__ xb, us* __restrict__ Wcb, us* __restrict__ VTb,
        us* __restrict__ headb, us* __restrict__ tailb, us* __restrict__ hvb) {
    int bid = blockIdx.x;
    if (bid < VT_BLOCKS) {
        __shared__ float4 red[8][32];            // [oct][col] 4 KB
        int cl = threadIdx.x & 31, q = threadIdx.x >> 5;   // col-lane, o-oct
        int c = bid * 32 + cl;                   // float4-column of V
        const float4* U4 = (const float4*)U;
        float4 acc = make_float4(0.f, 0.f, 0.f, 0.f);
        if (c < NC4) {
            int o0 = q * 25;
            #pragma unroll
            for (int o = o0; o < o0 + 25; ++o) { // 25 independent 16B loads
                float w = Wd[o];
                float4 u = U4[(size_t)o * NC4 + c];  // half-wave contiguous 512B
                acc.x += w * u.x; acc.y += w * u.y;
                acc.z += w * u.z; acc.w += w * u.w;
            }
        }
        red[q][cl] = acc;
        __syncthreads();
        if (q == 0 && c < NC4) {
            #pragma unroll
            for (int g = 1; g < 8; ++g) {
                float4 r = red[g][cl];
                acc.x += r.x; acc.y += r.y; acc.z += r.z; acc.w += r.w;
            }
            int i = c / (H / 4), j0 = (c % (H / 4)) * 4;  // V row i, cols j0..+3
            VTb[(j0 + 0) * KP + i] = f2bf(acc.x);         // VTb[n][k] = V[k][n]
            VTb[(j0 + 1) * KP + i] = f2bf(acc.y);
            VTb[(j0 + 2) * KP + i] = f2bf(acc.z);
            VTb[(j0 + 3) * KP + i] = f2bf(acc.w);
        }
        return;
    }
    const int GTH = (PREP_BLOCKS - VT_BLOCKS) * 256;
    int gtid = (bid - VT_BLOCKS) * 256 + threadIdx.x;
    // x -> bf16 (float4-vectorized; M*D/4 = 393216)
    {
        const float4* x4 = (const float4*)x;
        ushort4* xb4 = (ushort4*)xb;
        for (int t = gtid; t < M * D / 4; t += GTH) {
            float4 v = x4[t];
            ushort4 o; o.x = f2bf(v.x); o.y = f2bf(v.y); o.z = f2bf(v.z); o.w = f2bf(v.w);
            xb4[t] = o;
        }
    }
    // W transpose+concat -> bf16: Wcb[n*D+k] = W{h|t}[k][n]  (L2-resident rereads)
    for (int id = gtid; id < NCAT * D; id += GTH) {
        int n = id / D, k = id % D;
        float v = (n < H) ? Wh[k * H + n] : Wt[k * H + (n - H)];
        Wcb[id] = f2bf(v);
    }
    // pad zeroing (ws poisoned 0xAA every call)
    for (int id = gtid; id < M * (KP - H); id += GTH) {
        int r = id / (KP - H), c = H + id % (KP - H);
        headb[r * KP + c] = 0; tailb[r * KP + c] = 0;
    }
    for (int id = gtid; id < M * (KP - NP); id += GTH) {
        int r = id / (KP - NP), c = NP + id % (KP - NP);
        hvb[r * KP + c] = 0;
    }
    for (int id = gtid; id < H * (KP - H); id += GTH) {      // n<H, k in [H,KP)
        int n = id / (KP - H), k = H + id % (KP - H);
        VTb[n * KP + k] = 0;
    }
    for (int id = gtid; id < (NP - H) * KP; id += GTH) {     // n in [H,NP), all k
        int n = H + id / KP, k = id % KP;
        VTb[n * KP + k] = 0;
    }
}

// ---------------------------------------------------------------------------
// proj: C[2048,400] = xb[2048,768] @ Wcb^T; relu(+bias); split into headb|tailb
// One wave per 32x16 tile (verified round 2).
// ---------------------------------------------------------------------------
__global__ __launch_bounds__(64) void proj_mfma(
        const us* __restrict__ xb, const us* __restrict__ Wcb,
        const float* __restrict__ bh, const float* __restrict__ bt,
        us* __restrict__ headb, us* __restrict__ tailb) {
    int lane = threadIdx.x, quad = lane >> 4, col = lane & 15;
    int m0 = blockIdx.x * 32, n0 = blockIdx.y * 16;
    const bf16x8* A0 = (const bf16x8*)(xb + (m0 + col) * D + quad * 8);
    const bf16x8* A1 = (const bf16x8*)(xb + (m0 + 16 + col) * D + quad * 8);
    const bf16x8* Bp = (const bf16x8*)(Wcb + (n0 + col) * D + quad * 8);
    f32x4 acc0 = {0.f,0.f,0.f,0.f}, acc1 = {0.f,0.f,0.f,0.f};
    #pragma unroll 4
    for (int kk = 0; kk < D / 32; ++kk) {
        bf16x8 a0 = A0[kk * 4];
        bf16x8 a1 = A1[kk * 4];
        bf16x8 b  = Bp[kk * 4];
        acc0 = __builtin_amdgcn_mfma_f32_16x16x32_bf16(a0, b, acc0, 0, 0, 0);
        acc1 = __builtin_amdgcn_mfma_f32_16x16x32_bf16(a1, b, acc1, 0, 0, 0);
    }
    int n = n0 + col;
    // branch-free epilogue: head for n<H, tail otherwise
    bool ish = (n < H);
    float bias = ish ? bh[n] : bt[n - H];
    us* dst = ish ? headb : tailb;
    int nn = ish ? n : n - H;
    #pragma unroll
    for (int r = 0; r < 4; ++r) {
        int ma = m0 + quad * 4 + r;
        dst[ma * KP + nn]        = f2bf(fmaxf(acc0[r] + bias, 0.f));
        dst[(ma + 16) * KP + nn] = f2bf(fmaxf(acc1[r] + bias, 0.f));
    }
}

// ---------------------------------------------------------------------------
// hv[2048,208] = headb[2048,224] @ VTb[208,224]^T
// ---------------------------------------------------------------------------
__global__ __launch_bounds__(64) void hv_mfma(
        const us* __restrict__ headb, const us* __restrict__ VTb,
        us* __restrict__ hvb) {
    int lane = threadIdx.x, quad = lane >> 4, col = lane & 15;
    int m0 = blockIdx.x * 32, n0 = blockIdx.y * 16;
    const bf16x8* A0 = (const bf16x8*)(headb + (m0 + col) * KP + quad * 8);
    const bf16x8* A1 = (const bf16x8*)(headb + (m0 + 16 + col) * KP + quad * 8);
    const bf16x8* Bp = (const bf16x8*)(VTb + (n0 + col) * KP + quad * 8);
    f32x4 acc0 = {0.f,0.f,0.f,0.f}, acc1 = {0.f,0.f,0.f,0.f};
    #pragma unroll
    for (int kk = 0; kk < KP / 32; ++kk) {
        bf16x8 a0 = A0[kk * 4];
        bf16x8 a1 = A1[kk * 4];
        bf16x8 b  = Bp[kk * 4];
        acc0 = __builtin_amdgcn_mfma_f32_16x16x32_bf16(a0, b, acc0, 0, 0, 0);
        acc1 = __builtin_amdgcn_mfma_f32_16x16x32_bf16(a1, b, acc1, 0, 0, 0);
    }
    int n = n0 + col;
    #pragma unroll
    for (int r = 0; r < 4; ++r) {
        int ma = m0 + quad * 4 + r;
        hvb[ma * KP + n]        = f2bf(acc0[r]);
        hvb[(ma + 16) * KP + n] = f2bf(acc1[r]);
    }
}

// ---------------------------------------------------------------------------
// scores[b,x,y] = (hv[b,x,:].tail[b,y,:] + b_down)/sqrt(200); 32x32 per wave
// ---------------------------------------------------------------------------
__global__ __launch_bounds__(64) void scores_mfma(
        const us* __restrict__ hvb, const us* __restrict__ tailb,
        const float* __restrict__ bd, float* __restrict__ out) {
    int lane = threadIdx.x, quad = lane >> 4, col = lane & 15;
    int b = blockIdx.z;
    int m0 = blockIdx.x * 32, n0 = blockIdx.y * 32;
    const us* A  = hvb   + (size_t)b * S * KP;
    const us* Bm = tailb + (size_t)b * S * KP;
    const bf16x8* A0 = (const bf16x8*)(A  + (m0 + col) * KP + quad * 8);
    const bf16x8* A1 = (const bf16x8*)(A  + (m0 + 16 + col) * KP + quad * 8);
    const bf16x8* B0 = (const bf16x8*)(Bm + (n0 + col) * KP + quad * 8);
    const bf16x8* B1 = (const bf16x8*)(Bm + (n0 + 16 + col) * KP + quad * 8);
    f32x4 a00 = {0.f,0.f,0.f,0.f}, a01 = {0.f,0.f,0.f,0.f};
    f32x4 a10 = {0.f,0.f,0.f,0.f}, a11 = {0.f,0.f,0.f,0.f};
    #pragma unroll
    for (int kk = 0; kk < KP / 32; ++kk) {
        bf16x8 a0 = A0[kk * 4];
        bf16x8 a1 = A1[kk * 4];
        bf16x8 b0 = B0[kk * 4];
        bf16x8 b1 = B1[kk * 4];
        a00 = __builtin_amdgcn_mfma_f32_16x16x32_bf16(a0, b0, a00, 0, 0, 0);
        a01 = __builtin_amdgcn_mfma_f32_16x16x32_bf16(a0, b1, a01, 0, 0, 0);
        a10 = __builtin_amdgcn_mfma_f32_16x16x32_bf16(a1, b0, a10, 0, 0, 0);
        a11 = __builtin_amdgcn_mfma_f32_16x16x32_bf16(a1, b1, a11, 0, 0, 0);
    }
    float bias = bd[0];
    const float scale = 0.07071067811865475f;   // 1/sqrt(200)
    float* outb = out + (size_t)b * S * S;
    #pragma unroll
    for (int r = 0; r < 4; ++r) {
        int ma = m0 + quad * 4 + r, mb = ma + 16;
        outb[ma * S + n0 + col]      = (a00[r] + bias) * scale;
        outb[ma * S + n0 + 16 + col] = (a01[r] + bias) * scale;
        outb[mb * S + n0 + col]      = (a10[r] + bias) * scale;
        outb[mb * S + n0 + 16 + col] = (a11[r] + bias) * scale;
    }
}

extern "C" void kernel_launch(void* const* d_in, const int* in_sizes, int n_in,
                              void* d_out, int out_size, void* d_ws, size_t ws_size,
                              hipStream_t stream) {
    const float* x  = (const float*)d_in[0];
    const float* Wh = (const float*)d_in[1];
    const float* bh = (const float*)d_in[2];
    const float* Wt = (const float*)d_in[3];
    const float* bt = (const float*)d_in[4];
    const float* U  = (const float*)d_in[5];
    const float* Wd = (const float*)d_in[6];
    const float* bd = (const float*)d_in[7];
    float* out = (float*)d_out;

    // ws layout (bf16): xb | Wcb | VTb | hvb | headb | tailb  (~6.6 MB)
    us* xb    = (us*)d_ws;
    us* Wcb   = xb    + (size_t)M * D;
    us* VTb   = Wcb   + (size_t)NCAT * D;
    us* hvb   = VTb   + (size_t)NP * KP;
    us* headb = hvb   + (size_t)M * KP;
    us* tailb = headb + (size_t)M * KP;

    prep<<<PREP_BLOCKS, 256, 0, stream>>>(x, Wh, Wt, U, Wd,
                                          xb, Wcb, VTb, headb, tailb, hvb);
    proj_mfma<<<dim3(M / 32, NCAT / 16), 64, 0, stream>>>(xb, Wcb, bh, bt, headb, tailb);
    hv_mfma<<<dim3(M / 32, NP / 16), 64, 0, stream>>>(headb, VTb, hvb);
    scores_mfma<<<dim3(S / 32, S / 32, BATCH), 64, 0, stream>>>(hvb, tailb, bd, out);
}